// Round 2
// baseline (898.503 us; speedup 1.0000x reference)
//
#include <hip/hip_runtime.h>
#include <hip/hip_bf16.h>
#include <stdint.h>

// NNUE bucket model, fp16-MFMA plan (R1: +LDS XOR swizzle, +XCD-aware bid map):
//   K1: convert x (B,1540) fp32 -> x16 (2B,800) fp16 (pad 770->800), fused pc/bucket
//   K2: convert ft_w -> (512,800) fp16 padded, h1_w -> (256,1024) fp16
//   K3: GEMM1 (2B,800)x(512,800)^T -> crelu(+ft_b) -> C1 (2B,512) fp16
//   K4: GEMM2 (B,1024)x(256,1024)^T -> crelu(+h1_b) -> H (B,256) fp32
//   K5: tail: per sample, bucket-selected h2 (32x32) + h3 dot, 32 lanes/sample
//
// LDS swizzle: row r (64 B) holds 4 chunks of 16 B; slot s stores global chunk
// s ^ ((r>>1)&3). Fragment read for k-chunk rowQ uses slot rowQ ^ ((r>>1)&3).
// => each 16-lane quarter-wave covers all 32 banks exactly 2-way (free, m136),
// vs 8-way before (1.3e7 conflicts on gemm_ft).

#define INF 770
#define KP  800
#define FT  512
#define K2  1024
#define N2  256

typedef _Float16 half8 __attribute__((ext_vector_type(8)));
typedef float floatx4 __attribute__((ext_vector_type(4)));

__device__ __forceinline__ float crelu_f(float v) {
    return v < 0.f ? 0.f : (v > 1.f ? 1.f : v);
}

__device__ __forceinline__ void gl_lds16(const _Float16* g, _Float16* l) {
    __builtin_amdgcn_global_load_lds(
        (__attribute__((address_space(1))) void*)(uintptr_t)(const void*)g,
        (__attribute__((address_space(3))) void*)l,
        16, 0, 0);
}

// ---------------- K1: convert x + bucket ----------------
__global__ __launch_bounds__(256) void convert_x_kernel(
    const float* __restrict__ x, _Float16* __restrict__ x16,
    int* __restrict__ bucket, int B)
{
    __shared__ float red[4];
    int b = blockIdx.x;
    int tid = threadIdx.x, lane = tid & 63, w = tid >> 6;
    const float* src = x + (size_t)b * (2 * INF);
    _Float16* d0 = x16 + (size_t)b * KP;
    _Float16* d1 = x16 + ((size_t)B + b) * KP;
    float s = 0.f;
    for (int i = tid; i < KP; i += 256) {
        float v0 = 0.f, v1 = 0.f;
        if (i < INF) { v0 = src[i]; v1 = src[INF + i]; }
        d0[i] = (_Float16)v0;
        d1[i] = (_Float16)v1;
        if (i < 768) s += v0;
    }
    #pragma unroll
    for (int off = 32; off; off >>= 1) s += __shfl_down(s, off, 64);
    if (lane == 0) red[w] = s;
    __syncthreads();
    if (tid == 0) {
        float pc = red[0] + red[1] + red[2] + red[3];
        int bk = (int)(pc * (8.0f / 33.0f));
        bucket[b] = bk < 0 ? 0 : (bk > 7 ? 7 : bk);
    }
}

// ---------------- K2: convert weights ----------------
__global__ __launch_bounds__(256) void convert_w_kernel(
    const float* __restrict__ ftw, const float* __restrict__ h1w,
    _Float16* __restrict__ ftw16, _Float16* __restrict__ h1w16)
{
    int idx = blockIdx.x * 256 + threadIdx.x;
    const int FTW = FT * KP;            // 409600
    if (idx < FTW) {
        int r = idx / KP, c = idx - r * KP;
        ftw16[idx] = (_Float16)(c < INF ? ftw[r * INF + c] : 0.f);
    } else {
        int j = idx - FTW;
        if (j < N2 * K2) h1w16[j] = (_Float16)h1w[j];
    }
}

// ---------------- K3: GEMM1 (FT layer) ----------------
__global__ __launch_bounds__(256) void gemm_ft_kernel(
    const _Float16* __restrict__ A,   // (2B, 800)
    const _Float16* __restrict__ Bt,  // (512, 800)
    const float* __restrict__ bias,   // (512)
    _Float16* __restrict__ C)         // (2B, 512)
{
    __shared__ _Float16 lsA[128 * 32];
    __shared__ _Float16 lsB[128 * 32];
    // XCD-aware mapping: grid = 4096 = 1024 m-tiles x 4 n-tiles, 8 XCDs.
    // bid = g*8 + x  ->  mt = x*128 + (g>>2), nt = g&3: the 4 blocks sharing
    // an A-tile run back-to-back on ONE XCD -> A-tile hits that XCD's L2.
    int bid = blockIdx.x;
    int x = bid & 7, g = bid >> 3;
    int mt = x * 128 + (g >> 2), nt = g & 3;
    int m0 = mt * 128, n0 = nt * 128;
    int tid = threadIdx.x, lane = tid & 63, w = tid >> 6;
    int rm = (w & 1) * 64, rn = (w >> 1) * 64;
    int colL = lane & 15, rowQ = lane >> 4;
    int chA = rowQ ^ ((colL >> 1) & 3);   // swizzled chunk slot (lane-const)

    floatx4 acc[4][4] = {};

    for (int kt = 0; kt < KP / 32; ++kt) {
        int ks = kt * 32;
        #pragma unroll
        for (int p = 0; p < 2; ++p) {
            int qb = p * 256 + w * 64;
            int q = qb + lane;
            int r = q >> 2;
            int c8 = (q & 3) ^ ((r >> 1) & 3);   // store swizzled
            gl_lds16(A + (size_t)(m0 + r) * KP + ks + c8 * 8, lsA + qb * 8);
            gl_lds16(Bt + (size_t)(n0 + r) * KP + ks + c8 * 8, lsB + qb * 8);
        }
        asm volatile("s_waitcnt vmcnt(0)" ::: "memory");
        __syncthreads();

        half8 af[4], bf[4];
        #pragma unroll
        for (int i = 0; i < 4; ++i)
            af[i] = *(const half8*)(lsA + (rm + i * 16 + colL) * 32 + chA * 8);
        #pragma unroll
        for (int j = 0; j < 4; ++j)
            bf[j] = *(const half8*)(lsB + (rn + j * 16 + colL) * 32 + chA * 8);
        #pragma unroll
        for (int i = 0; i < 4; ++i)
            #pragma unroll
            for (int j = 0; j < 4; ++j)
                acc[i][j] = __builtin_amdgcn_mfma_f32_16x16x32_f16(af[i], bf[j], acc[i][j], 0, 0, 0);
        __syncthreads();
    }

    #pragma unroll
    for (int j = 0; j < 4; ++j) {
        int gn = n0 + rn + j * 16 + colL;
        float bv = bias[gn];
        #pragma unroll
        for (int i = 0; i < 4; ++i) {
            #pragma unroll
            for (int r = 0; r < 4; ++r) {
                int gm = m0 + rm + i * 16 + rowQ * 4 + r;
                float v = crelu_f(acc[i][j][r] + bv);
                C[(size_t)gm * FT + gn] = (_Float16)v;
            }
        }
    }
}

// ---------------- K4: GEMM2 (h1 layer, all buckets) ----------------
__global__ __launch_bounds__(256) void gemm_h1_kernel(
    const _Float16* __restrict__ C1,  // (2B, 512)
    const _Float16* __restrict__ Bt,  // (256, 1024)
    const float* __restrict__ bias,   // (256)
    float* __restrict__ H,            // (B, 256)
    int B)
{
    __shared__ _Float16 lsA[128 * 32];
    __shared__ _Float16 lsB[128 * 32];
    // grid = 1024 = 512 m-tiles x 2 n-tiles; bid = g*8+x -> mt = x*64+(g>>1)
    int bid = blockIdx.x;
    int x = bid & 7, g = bid >> 3;
    int mt = x * 64 + (g >> 1), nt = g & 1;
    int m0 = mt * 128, n0 = nt * 128;
    int tid = threadIdx.x, lane = tid & 63, w = tid >> 6;
    int rm = (w & 1) * 64, rn = (w >> 1) * 64;
    int colL = lane & 15, rowQ = lane >> 4;
    int chA = rowQ ^ ((colL >> 1) & 3);

    floatx4 acc[4][4] = {};

    for (int kt = 0; kt < K2 / 32; ++kt) {
        int ks = kt * 32;
        // combined[m][k] = k<512 ? C1[m][k] : C1[B+m][k-512]
        const _Float16* Abase = (ks < FT) ? (C1 + ks)
                                          : (C1 + (size_t)B * FT + (ks - FT));
        #pragma unroll
        for (int p = 0; p < 2; ++p) {
            int qb = p * 256 + w * 64;
            int q = qb + lane;
            int r = q >> 2;
            int c8 = (q & 3) ^ ((r >> 1) & 3);
            gl_lds16(Abase + (size_t)(m0 + r) * FT + c8 * 8, lsA + qb * 8);
            gl_lds16(Bt + (size_t)(n0 + r) * K2 + ks + c8 * 8, lsB + qb * 8);
        }
        asm volatile("s_waitcnt vmcnt(0)" ::: "memory");
        __syncthreads();

        half8 af[4], bf[4];
        #pragma unroll
        for (int i = 0; i < 4; ++i)
            af[i] = *(const half8*)(lsA + (rm + i * 16 + colL) * 32 + chA * 8);
        #pragma unroll
        for (int j = 0; j < 4; ++j)
            bf[j] = *(const half8*)(lsB + (rn + j * 16 + colL) * 32 + chA * 8);
        #pragma unroll
        for (int i = 0; i < 4; ++i)
            #pragma unroll
            for (int j = 0; j < 4; ++j)
                acc[i][j] = __builtin_amdgcn_mfma_f32_16x16x32_f16(af[i], bf[j], acc[i][j], 0, 0, 0);
        __syncthreads();
    }

    #pragma unroll
    for (int j = 0; j < 4; ++j) {
        int gn = n0 + rn + j * 16 + colL;
        float bv = bias[gn];
        #pragma unroll
        for (int i = 0; i < 4; ++i) {
            #pragma unroll
            for (int r = 0; r < 4; ++r) {
                int gm = m0 + rm + i * 16 + rowQ * 4 + r;
                H[(size_t)gm * N2 + gn] = crelu_f(acc[i][j][r] + bv);
            }
        }
    }
}

// ---------------- K5: tail (h2 + h3, bucket-selected) ----------------
__global__ __launch_bounds__(256) void tail_kernel(
    const float* __restrict__ H,       // (B, 256), already crelu'd h1
    const int* __restrict__ bucket,
    const float* __restrict__ h2w,     // (8,32,32)
    const float* __restrict__ h2b,     // (8,32)
    const float* __restrict__ h3w,     // (8,1,32)
    const float* __restrict__ h3b,     // (8,1)
    float* __restrict__ out, int B)
{
    int s = blockIdx.x * 8 + (threadIdx.x >> 5);
    int j = threadIdx.x & 31;
    if (s >= B) return;
    int k = bucket[s];
    float h1v = H[(size_t)s * N2 + k * 32 + j];
    const float* w2 = h2w + ((k * 32 + j) * 32);
    float a = h2b[k * 32 + j];
    #pragma unroll
    for (int i = 0; i < 32; ++i) a += w2[i] * __shfl(h1v, i, 32);
    a = crelu_f(a);
    float p = a * h3w[k * 32 + j];
    #pragma unroll
    for (int off = 16; off; off >>= 1) p += __shfl_down(p, off, 32);
    if (j == 0) out[s] = p + h3b[k];
}

extern "C" void kernel_launch(void* const* d_in, const int* in_sizes, int n_in,
                              void* d_out, int out_size, void* d_ws, size_t ws_size,
                              hipStream_t stream) {
    const float* x    = (const float*)d_in[0];
    const float* ftw  = (const float*)d_in[1];
    const float* ftb  = (const float*)d_in[2];
    const float* h1w  = (const float*)d_in[3];
    const float* h1b  = (const float*)d_in[4];
    const float* h2w  = (const float*)d_in[5];
    const float* h2b  = (const float*)d_in[6];
    const float* h3w  = (const float*)d_in[7];
    const float* h3b  = (const float*)d_in[8];
    float* out = (float*)d_out;

    int B = in_sizes[0] / (2 * INF);          // 65536

    // workspace layout
    char* ws = (char*)d_ws;
    _Float16* x16   = (_Float16*)ws;                          // 2B*800*2
    size_t x16_b    = (size_t)2 * B * KP * sizeof(_Float16);
    _Float16* C1    = (_Float16*)(ws + x16_b);                // 2B*512*2
    size_t c1_b     = (size_t)2 * B * FT * sizeof(_Float16);
    _Float16* ftw16 = (_Float16*)(ws + x16_b + c1_b);         // 512*800*2
    _Float16* h1w16 = ftw16 + (size_t)FT * KP;                // 256*1024*2
    int* bucket     = (int*)(h1w16 + (size_t)N2 * K2);        // B*4
    float* H        = (float*)ws;                             // alias x16 (dead after GEMM1)

    // K2: weights (independent of K1)
    {
        int total = FT * KP + N2 * K2;
        convert_w_kernel<<<(total + 255) / 256, 256, 0, stream>>>(ftw, h1w, ftw16, h1w16);
    }
    // K1: x conversion + bucket
    convert_x_kernel<<<B, 256, 0, stream>>>(x, x16, bucket, B);
    // K3: FT GEMM
    {
        int grid = (2 * B / 128) * 4;       // 4096
        gemm_ft_kernel<<<grid, 256, 0, stream>>>(x16, ftw16, ftb, C1);
    }
    // K4: h1 GEMM
    {
        int grid = (B / 128) * 2;           // 1024
        gemm_h1_kernel<<<grid, 256, 0, stream>>>(C1, h1w16, h1b, H, B);
    }
    // K5: tail
    tail_kernel<<<(B + 7) / 8, 256, 0, stream>>>(H, bucket, h2w, h2b, h3w, h3b, out, B);
}

// Round 3
// 799.406 us; speedup vs baseline: 1.1240x; 1.1240x over previous
//
#include <hip/hip_runtime.h>
#include <hip/hip_bf16.h>
#include <stdint.h>

// NNUE bucket model R3: convert_x ELIMINATED (fused into gemm_ft), fan-out cut.
//   K2: convert ft_w -> (512,800) fp16 padded, h1_w -> (256,1024) fp16
//   K3: gemm_ft_fused: A = x fp32 read directly (float2 loads -> v_cvt -> ds_write),
//       pc/bucket computed during staging; B via global_load_lds.
//       BM=128 BN=256 BK=32, 512 thr / 8 waves (2m x 4n), wave-tile 64x64.
//       24 full k-iters (k<768) + 1 edge iter (k=768,769 real, rest zero).
//   K4: gemm_h1: BM=64, BN=256 (FULL N -> C1 read once), 512 thr, 32 k-iters.
//   K5: tail unchanged.
// LDS chunk-XOR swizzle throughout (R2: conflicts 1.3e7 -> 0).

#define INF  770
#define XROW 1540
#define KP   800
#define FT   512
#define K2   1024
#define N2   256

typedef _Float16 half8 __attribute__((ext_vector_type(8)));
typedef float floatx4 __attribute__((ext_vector_type(4)));
typedef float floatx2 __attribute__((ext_vector_type(2)));

__device__ __forceinline__ float crelu_f(float v) {
    return v < 0.f ? 0.f : (v > 1.f ? 1.f : v);
}

__device__ __forceinline__ void gl_lds16(const _Float16* g, _Float16* l) {
    __builtin_amdgcn_global_load_lds(
        (__attribute__((address_space(1))) void*)(uintptr_t)(const void*)g,
        (__attribute__((address_space(3))) void*)l,
        16, 0, 0);
}

// ---------------- K2: convert weights ----------------
__global__ __launch_bounds__(256) void convert_w_kernel(
    const float* __restrict__ ftw, const float* __restrict__ h1w,
    _Float16* __restrict__ ftw16, _Float16* __restrict__ h1w16)
{
    int idx = blockIdx.x * 256 + threadIdx.x;
    const int FTW = FT * KP;            // 409600
    if (idx < FTW) {
        int r = idx / KP, c = idx - r * KP;
        ftw16[idx] = (_Float16)(c < INF ? ftw[r * INF + c] : 0.f);
    } else {
        int j = idx - FTW;
        if (j < N2 * K2) h1w16[j] = (_Float16)h1w[j];
    }
}

// ---------------- K3: fused FT GEMM ----------------
__global__ __launch_bounds__(512, 4) void gemm_ft_fused(
    const float* __restrict__ x,      // (B, 1540)
    const _Float16* __restrict__ Bt,  // (512, 800) padded fp16
    const float* __restrict__ bias,   // (512)
    _Float16* __restrict__ C,         // (2B, 512)
    int* __restrict__ bucket, int B)
{
    __shared__ _Float16 lsA[128 * 32];   // 8 KB
    __shared__ _Float16 lsB[256 * 32];   // 16 KB
    // XCD pairing: bid%8 = XCD; the 2 n-blocks of an m-tile run adjacent on
    // one XCD so the 2nd read of the fp32 A-tile (788 KB) hits that L2.
    int bid = blockIdx.x;
    int xcd = bid & 7, g = bid >> 3;
    int nt = g & 1, mt = (g >> 1) * 8 + xcd;      // mt in [0,1024)
    int m0 = mt * 128, n0 = nt * 256;
    int tid = threadIdx.x, lane = tid & 63, w = tid >> 6;
    int rm = (w & 1) * 64, rn = (w >> 1) * 64;
    int colL = lane & 15, rowQ = lane >> 4;
    int chA = rowQ ^ ((colL >> 1) & 3);

    // A staging identity: thread -> (row, 16B chunk kq)
    int arow = tid >> 2, kq = tid & 3;
    const float* asrc = (m0 < B)
        ? x + (size_t)(m0 + arow) * XROW
        : x + (size_t)(m0 - B + arow) * XROW + INF;
    _Float16* adst = lsA + arow * 32 + (kq ^ ((arow >> 1) & 3)) * 8;

    floatx4 acc[4][4] = {};
    float psum = 0.f;

    for (int kt = 0; kt < 25; ++kt) {
        int ks = kt * 32;
        // ---- A: fp32 -> fp16 in registers -> LDS ----
        half8 hv = {};
        if (kt < 24) {
            const float* p = asrc + ks + kq * 8;
            floatx2 f0 = *(const floatx2*)(p);
            floatx2 f1 = *(const floatx2*)(p + 2);
            floatx2 f2 = *(const floatx2*)(p + 4);
            floatx2 f3 = *(const floatx2*)(p + 6);
            hv[0] = (_Float16)f0.x; hv[1] = (_Float16)f0.y;
            hv[2] = (_Float16)f1.x; hv[3] = (_Float16)f1.y;
            hv[4] = (_Float16)f2.x; hv[5] = (_Float16)f2.y;
            hv[6] = (_Float16)f3.x; hv[7] = (_Float16)f3.y;
            psum += (f0.x + f0.y) + (f1.x + f1.y) + (f2.x + f2.y) + (f3.x + f3.y);
        } else if (kq == 0) {
            // k = 768,769 real; 770..799 zero (pad)
            floatx2 f0 = *(const floatx2*)(asrc + 768);
            hv[0] = (_Float16)f0.x; hv[1] = (_Float16)f0.y;
        }
        *(half8*)adst = hv;
        // ---- B: global_load_lds, swizzled ----
        #pragma unroll
        for (int p = 0; p < 2; ++p) {
            int idx = p * 512 + tid;
            int br = idx >> 2, bs = (idx & 3) ^ ((br >> 1) & 3);
            gl_lds16(Bt + (size_t)(n0 + br) * KP + ks + bs * 8, lsB + idx * 8);
        }
        asm volatile("s_waitcnt vmcnt(0)" ::: "memory");
        __syncthreads();

        half8 af[4], bf[4];
        #pragma unroll
        for (int i = 0; i < 4; ++i)
            af[i] = *(const half8*)(lsA + (rm + i * 16 + colL) * 32 + chA * 8);
        #pragma unroll
        for (int j = 0; j < 4; ++j)
            bf[j] = *(const half8*)(lsB + (rn + j * 16 + colL) * 32 + chA * 8);
        #pragma unroll
        for (int i = 0; i < 4; ++i)
            #pragma unroll
            for (int j = 0; j < 4; ++j)
                acc[i][j] = __builtin_amdgcn_mfma_f32_16x16x32_f16(af[i], bf[j], acc[i][j], 0, 0, 0);
        __syncthreads();
    }

    // ---- bucket (pc = sum x[:, :768], exactly the 24 full iters) ----
    psum += __shfl_xor(psum, 1, 64);
    psum += __shfl_xor(psum, 2, 64);
    if (nt == 0 && m0 < B && (tid & 3) == 0) {
        int bk = (int)(psum * (8.0f / 33.0f));
        bucket[m0 + arow] = bk < 0 ? 0 : (bk > 7 ? 7 : bk);
    }

    // ---- epilogue ----
    #pragma unroll
    for (int j = 0; j < 4; ++j) {
        int gn = n0 + rn + j * 16 + colL;
        float bv = bias[gn];
        #pragma unroll
        for (int i = 0; i < 4; ++i) {
            #pragma unroll
            for (int r = 0; r < 4; ++r) {
                int gm = m0 + rm + i * 16 + rowQ * 4 + r;
                C[(size_t)gm * FT + gn] = (_Float16)crelu_f(acc[i][j][r] + bv);
            }
        }
    }
}

// ---------------- K4: h1 GEMM (full-N blocks, C1 read once) ----------------
__global__ __launch_bounds__(512, 4) void gemm_h1_kernel(
    const _Float16* __restrict__ C1,  // (2B, 512)
    const _Float16* __restrict__ Bt,  // (256, 1024)
    const float* __restrict__ bias,   // (256)
    float* __restrict__ H,            // (B, 256)
    int B)
{
    __shared__ _Float16 lsA[64 * 32];    // 4 KB
    __shared__ _Float16 lsB[256 * 32];   // 16 KB
    int m0 = blockIdx.x * 64;
    int tid = threadIdx.x, lane = tid & 63, w = tid >> 6;   // 8 waves: n-slice 32 each
    int colL = lane & 15, rowQ = lane >> 4;
    int chA = rowQ ^ ((colL >> 1) & 3);

    floatx4 acc[4][2] = {};

    for (int kt = 0; kt < 32; ++kt) {
        int ks = kt * 32;
        // combined[m][k] = k<512 ? C1[m][k] : C1[B+m][k-512]
        const _Float16* Abase = (ks < FT) ? (C1 + (size_t)m0 * FT + ks)
                                          : (C1 + (size_t)(B + m0) * FT + (ks - FT));
        if (tid < 256) {   // waves 0-3 stage A (4 KB)
            int br = tid >> 2, bs = (tid & 3) ^ ((br >> 1) & 3);
            gl_lds16(Abase + (size_t)br * FT + bs * 8, lsA + tid * 8);
        }
        #pragma unroll
        for (int p = 0; p < 2; ++p) {
            int idx = p * 512 + tid;
            int br = idx >> 2, bs = (idx & 3) ^ ((br >> 1) & 3);
            gl_lds16(Bt + (size_t)br * K2 + ks + bs * 8, lsB + idx * 8);
        }
        asm volatile("s_waitcnt vmcnt(0)" ::: "memory");
        __syncthreads();

        half8 af[4], bf[2];
        #pragma unroll
        for (int i = 0; i < 4; ++i)
            af[i] = *(const half8*)(lsA + (i * 16 + colL) * 32 + chA * 8);
        #pragma unroll
        for (int j = 0; j < 2; ++j)
            bf[j] = *(const half8*)(lsB + (w * 32 + j * 16 + colL) * 32 + chA * 8);
        #pragma unroll
        for (int i = 0; i < 4; ++i)
            #pragma unroll
            for (int j = 0; j < 2; ++j)
                acc[i][j] = __builtin_amdgcn_mfma_f32_16x16x32_f16(af[i], bf[j], acc[i][j], 0, 0, 0);
        __syncthreads();
    }

    #pragma unroll
    for (int j = 0; j < 2; ++j) {
        int gn = w * 32 + j * 16 + colL;
        float bv = bias[gn];
        #pragma unroll
        for (int i = 0; i < 4; ++i) {
            #pragma unroll
            for (int r = 0; r < 4; ++r) {
                int gm = m0 + i * 16 + rowQ * 4 + r;
                H[(size_t)gm * N2 + gn] = crelu_f(acc[i][j][r] + bv);
            }
        }
    }
}

// ---------------- K5: tail (h2 + h3, bucket-selected) ----------------
__global__ __launch_bounds__(256) void tail_kernel(
    const float* __restrict__ H,
    const int* __restrict__ bucket,
    const float* __restrict__ h2w,     // (8,32,32)
    const float* __restrict__ h2b,     // (8,32)
    const float* __restrict__ h3w,     // (8,1,32)
    const float* __restrict__ h3b,     // (8,1)
    float* __restrict__ out, int B)
{
    int s = blockIdx.x * 8 + (threadIdx.x >> 5);
    int j = threadIdx.x & 31;
    if (s >= B) return;
    int k = bucket[s];
    float h1v = H[(size_t)s * N2 + k * 32 + j];
    const float* w2 = h2w + ((k * 32 + j) * 32);
    float a = h2b[k * 32 + j];
    #pragma unroll
    for (int i = 0; i < 32; ++i) a += w2[i] * __shfl(h1v, i, 32);
    a = crelu_f(a);
    float p = a * h3w[k * 32 + j];
    #pragma unroll
    for (int off = 16; off; off >>= 1) p += __shfl_down(p, off, 32);
    if (j == 0) out[s] = p + h3b[k];
}

extern "C" void kernel_launch(void* const* d_in, const int* in_sizes, int n_in,
                              void* d_out, int out_size, void* d_ws, size_t ws_size,
                              hipStream_t stream) {
    const float* x    = (const float*)d_in[0];
    const float* ftw  = (const float*)d_in[1];
    const float* ftb  = (const float*)d_in[2];
    const float* h1w  = (const float*)d_in[3];
    const float* h1b  = (const float*)d_in[4];
    const float* h2w  = (const float*)d_in[5];
    const float* h2b  = (const float*)d_in[6];
    const float* h3w  = (const float*)d_in[7];
    const float* h3b  = (const float*)d_in[8];
    float* out = (float*)d_out;

    int B = in_sizes[0] / (2 * INF);          // 65536

    // workspace layout
    char* ws = (char*)d_ws;
    _Float16* C1    = (_Float16*)ws;                          // 2B*512*2 = 134 MB
    size_t c1_b     = (size_t)2 * B * FT * sizeof(_Float16);
    _Float16* ftw16 = (_Float16*)(ws + c1_b);                 // 512*800*2
    size_t ftw_b    = (size_t)FT * KP * sizeof(_Float16);
    _Float16* h1w16 = (_Float16*)(ws + c1_b + ftw_b);         // 256*1024*2
    size_t h1w_b    = (size_t)N2 * K2 * sizeof(_Float16);
    int* bucket     = (int*)(ws + c1_b + ftw_b + h1w_b);      // B*4
    size_t bk_b     = (size_t)B * sizeof(int);
    float* H        = (float*)(ws + c1_b + ftw_b + h1w_b + bk_b); // B*256*4

    // K2: weights
    {
        int total = FT * KP + N2 * K2;
        convert_w_kernel<<<(total + 255) / 256, 256, 0, stream>>>(ftw, h1w, ftw16, h1w16);
    }
    // K3: fused FT GEMM (+bucket)
    gemm_ft_fused<<<(2 * B / 128) * 2, 512, 0, stream>>>(x, ftw16, ftb, C1, bucket, B);
    // K4: h1 GEMM
    gemm_h1_kernel<<<B / 64, 512, 0, stream>>>(C1, h1w16, h1b, H, B);
    // K5: tail
    tail_kernel<<<(B + 7) / 8, 256, 0, stream>>>(H, bucket, h2w, h2b, h3w, h3b, out, B);
}